// Round 2
// baseline (635.672 us; speedup 1.0000x reference)
//
#include <hip/hip_runtime.h>
#include <hip/hip_bf16.h>
#include <cstdint>

#define B_  64
#define T_  32
#define E_  300
#define EP  320      // padded K for the x-precompute GEMM
#define H_  1024
#define G4  4096     // 4*H
#define BH  65536    // B_*H_
#define NBLK 192     // persistent blocks: 64 L1 + 64 I2 + 64 H2

typedef __attribute__((ext_vector_type(8))) short bf16x8;
typedef __attribute__((ext_vector_type(4))) float f32x4;
typedef unsigned short ushort_t;

__device__ __forceinline__ bf16x8 load_b8(const ushort_t* p) {
    union { uint4 u; bf16x8 v; } c;
    c.u = *reinterpret_cast<const uint4*>(p);
    return c.v;
}

__device__ __forceinline__ ushort_t f2bf(float x) {
    union { float f; uint32_t u; } c; c.f = x;
    uint32_t r = c.u + 0x7fffu + ((c.u >> 16) & 1u);   // RNE
    return (ushort_t)(r >> 16);
}

__device__ __forceinline__ float sigm(float x) { return 1.0f / (1.0f + __expf(-x)); }

// agent-scope (cross-XCD write-through) stores for produced data; plain loads
// are used on the consumer side (unique buffer per timestep => no stale lines)
__device__ __forceinline__ void astore64(uint64_t* p, uint64_t v) {
    __hip_atomic_store(p, v, __ATOMIC_RELAXED, __HIP_MEMORY_SCOPE_AGENT);
}
__device__ __forceinline__ uint64_t packf2(float a, float b) {
    union { float f[2]; uint64_t u; } c; c.f[0] = a; c.f[1] = b; return c.u;
}

// ---- decoupled dataflow barrier: 4 cache lines per (t, role) ----
__device__ __forceinline__ void arrive(int* ctr, int t, int role, int js) {
    __hip_atomic_fetch_add(&ctr[((t * 3 + role) * 4 + (js & 3)) * 32], 1,
                           __ATOMIC_RELAXED, __HIP_MEMORY_SCOPE_AGENT);
}
__device__ __forceinline__ void waitc(int* ctr, int t, int role) {
    int sum;
    do {
        sum = 0;
        #pragma unroll
        for (int k = 0; k < 4; ++k)
            sum += __hip_atomic_load(&ctr[((t * 3 + role) * 4 + k) * 32],
                                     __ATOMIC_RELAXED, __HIP_MEMORY_SCOPE_AGENT);
        if (sum < 64) __builtin_amdgcn_s_sleep(1);
    } while (sum < 64);
}

// ---------------- fused prep kernel ----------------
// blocks [0,1280): embed gather+pad ; [1280,3328): W_ih1 pad+convert
__global__ void prep_inputs(const int* __restrict__ q, const float* __restrict__ table,
                            ushort_t* __restrict__ Xp,
                            const float* __restrict__ Wsrc, ushort_t* __restrict__ Wdst) {
    int blk = blockIdx.x;
    if (blk < 1280) {
        int i = blk * 256 + threadIdx.x;
        const int n = B_ * T_ * EP;
        for (; i < n; i += 1280 * 256) {
            int r = i / EP, c = i - r * EP;
            Xp[i] = (c < E_) ? f2bf(table[q[r] * E_ + c]) : (ushort_t)0;
        }
    } else {
        int i = (blk - 1280) * 256 + threadIdx.x;
        const int n = G4 * EP;
        for (; i < n; i += 2048 * 256) {
            int r = i / EP, c = i - r * EP;
            Wdst[i] = (c < E_) ? f2bf(Wsrc[r * E_ + c]) : (ushort_t)0;
        }
    }
}

// ---------------- x-part precompute GEMM ----------------
// xg[t][b][4H] = Xp @ Wih1p^T + (b_ih1+b_hh1)
__launch_bounds__(256)
__global__ void xgemm(const ushort_t* __restrict__ Xp, const ushort_t* __restrict__ Wp,
                      const float* __restrict__ b_ih1, const float* __restrict__ b_hh1,
                      float* __restrict__ xg) {
    int mblk = blockIdx.x, nblk = blockIdx.y;
    int wave = threadIdx.x >> 6, lane = threadIdx.x & 63;
    int lm = lane & 15, lq = lane >> 4;
    int m0 = mblk * 64 + wave * 16;
    f32x4 acc[4];
    #pragma unroll
    for (int g = 0; g < 4; ++g) {
        int n = nblk * 64 + g * 16 + lm;
        float bv = b_ih1[n] + b_hh1[n];
        acc[g] = (f32x4){bv, bv, bv, bv};
    }
    for (int k0 = 0; k0 < EP; k0 += 32) {
        bf16x8 a = load_b8(Xp + (m0 + lm) * EP + k0 + lq * 8);
        #pragma unroll
        for (int g = 0; g < 4; ++g) {
            bf16x8 b = load_b8(Wp + (nblk * 64 + g * 16 + lm) * EP + k0 + lq * 8);
            acc[g] = __builtin_amdgcn_mfma_f32_16x16x32_bf16(a, b, acc[g], 0, 0, 0);
        }
    }
    #pragma unroll
    for (int g = 0; g < 4; ++g)
        #pragma unroll
        for (int r = 0; r < 4; ++r) {
            int m = m0 + lq * 4 + r;          // m = b*T + t
            int b = m >> 5, t = m & 31;
            int n = nblk * 64 + g * 16 + lm;
            xg[((size_t)t * B_ + b) * G4 + n] = acc[g][r];
        }
}

// ---------------- persistent recurrence kernel ----------------
// blocks 0-63: L1 (Whh1), 64-127: I2 (Wih2), 128-191: H2 (Whh2)

// full-depth prefetch: all 32 uint4 h-loads in flight (128 VGPRs; 132KB LDS
// caps us at 1 block/CU -> 1 wave/SIMD -> up to 512 VGPRs without occupancy cost)
__device__ __forceinline__ void gemm_k1024(const ushort_t* __restrict__ hvec,
                                           const ushort_t (*w)[1032],
                                           int lm, int lq, int m0, f32x4 acc[4]) {
    const uint4* hr = reinterpret_cast<const uint4*>(hvec + (size_t)(m0 + lm) * H_);
    uint4 buf[32];
    #pragma unroll
    for (int grp = 0; grp < 4; ++grp)
        #pragma unroll
        for (int i = 0; i < 8; ++i)
            buf[grp * 8 + i] = hr[grp * 32 + i * 4 + lq];
    #pragma unroll
    for (int grp = 0; grp < 4; ++grp)
        #pragma unroll
        for (int i = 0; i < 8; ++i) {
            int k0 = grp * 256 + i * 32;
            union { uint4 u; bf16x8 v; } a; a.u = buf[grp * 8 + i];
            #pragma unroll
            for (int g = 0; g < 4; ++g) {
                bf16x8 bb = load_b8(&w[g * 16 + lm][k0 + lq * 8]);
                acc[g] = __builtin_amdgcn_mfma_f32_16x16x32_bf16(a.v, bb, acc[g], 0, 0, 0);
            }
        }
}

__device__ __forceinline__ void lstm_elem(const f32x4 acc[4], int r,
                                          float* c, float* h, ushort_t* hb) {
    float iv = sigm(acc[0][r]);
    float fv = sigm(acc[1][r]);
    float gv = tanhf(acc[2][r]);
    float ov = sigm(acc[3][r]);
    float cn = fv * c[r] + iv * gv;
    float hv = ov * tanhf(cn);
    c[r] = cn; h[r] = hv; hb[r] = f2bf(hv);
}

// repacked h-tile store: 256 coalesced 8-byte agent stores (was 1024 x 2B)
__device__ __forceinline__ void store_h_tile(ushort_t* dst, int js, const ushort_t* hst) {
    int tid = threadIdx.x;
    uint64_t v = reinterpret_cast<const uint64_t*>(hst)[tid];
    astore64(reinterpret_cast<uint64_t*>(dst + (size_t)(tid >> 2) * H_ + js * 16) + (tid & 3), v);
}

__global__ __launch_bounds__(256) void lstm_persist(
    const float* __restrict__ Whh1, const float* __restrict__ Wih2,
    const float* __restrict__ Whh2,
    const float* __restrict__ b_ih2, const float* __restrict__ b_hh2,
    const float* __restrict__ xg, const int* __restrict__ qlen,
    ushort_t* __restrict__ h1hist,   // 33 slots of BH bf16; slot k = h1(k-1)
    ushort_t* __restrict__ h2hist,   // 33 slots of BH bf16; slot k = h2(k-1)
    float* __restrict__ Qhist,       // 32 slots of BH*4 fp32, gate-interleaved [b][j][4]
    float* __restrict__ h1f, float* __restrict__ c1f,
    float* __restrict__ h2f, float* __restrict__ c2f,
    int* __restrict__ ctr)
{
    __shared__ ushort_t ws[64][1032];              // 132,096 B
    __shared__ __align__(16) ushort_t hstage[64][16];  // 2,048 B -> still 1 block/CU

    const int blk  = blockIdx.x;
    const int role = blk >> 6;          // 0=L1, 1=I2, 2=H2
    const int js   = blk & 63;
    const int wave = threadIdx.x >> 6, lane = threadIdx.x & 63;
    const int lm = lane & 15, lq = lane >> 4;
    const int m0 = wave * 16;

    // ---- stage weight slice fp32 -> bf16 into LDS (once) ----
    const float* Wsrc = (role == 0) ? Whh1 : (role == 1) ? Wih2 : Whh2;
    for (int idx = threadIdx.x; idx < 64 * 256; idx += 256) {
        int r = idx >> 8, c4 = idx & 255;
        int grow = (r >> 4) * H_ + js * 16 + (r & 15);
        float4 v = reinterpret_cast<const float4*>(Wsrc + (size_t)grow * H_)[c4];
        uint2 pk;
        pk.x = (uint32_t)f2bf(v.x) | ((uint32_t)f2bf(v.y) << 16);
        pk.y = (uint32_t)f2bf(v.z) | ((uint32_t)f2bf(v.w) << 16);
        *reinterpret_cast<uint2*>(&ws[r][c4 * 4]) = pk;
    }
    __syncthreads();

    int q[4];
    #pragma unroll
    for (int r = 0; r < 4; ++r) q[r] = qlen[m0 + lq * 4 + r];

    float    c_reg[4]  = {0.f, 0.f, 0.f, 0.f};
    float    h_reg[4]  = {0.f, 0.f, 0.f, 0.f};
    ushort_t hb_reg[4] = {0, 0, 0, 0};

    if (role == 0) {
        // ---- layer-1 recurrence: dep only on itself (64-block group) ----
        for (int t = 0; t < T_; ++t) {
            f32x4 acc[4];                       // xg loads issue before the wait
            #pragma unroll
            for (int g = 0; g < 4; ++g)
                #pragma unroll
                for (int r = 0; r < 4; ++r)
                    acc[g][r] = xg[((size_t)t * B_ + (m0 + lq * 4 + r)) * G4 + g * H_ + js * 16 + lm];
            if (t > 0) {
                if (threadIdx.x == 0) waitc(ctr, t - 1, 0);   // h1 slot t complete
                __syncthreads();
            }
            gemm_k1024(h1hist + (size_t)t * BH, ws, lm, lq, m0, acc);
            #pragma unroll
            for (int r = 0; r < 4; ++r) {
                if (t < q[r]) lstm_elem(acc, r, c_reg, h_reg, hb_reg);
                hstage[m0 + lq * 4 + r][lm] = hb_reg[r];
            }
            __syncthreads();
            store_h_tile(h1hist + (size_t)(t + 1) * BH, js, &hstage[0][0]);
            __syncthreads();                    // drains vmcnt(0): stores visible at L3
            if (threadIdx.x == 0) arrive(ctr, t, 0, js);
        }
        #pragma unroll
        for (int r = 0; r < 4; ++r) {
            int b = m0 + lq * 4 + r, j = js * 16 + lm;
            h1f[b * H_ + j] = h_reg[r]; c1f[b * H_ + j] = c_reg[r];
        }
    } else if (role == 1) {
        // ---- Q(t) = Wih2 . h1(t) + bias2 : dep only on role0[t] ----
        float bi[4];
        #pragma unroll
        for (int g = 0; g < 4; ++g) {
            int n = g * H_ + js * 16 + lm;
            bi[g] = b_ih2[n] + b_hh2[n];
        }
        for (int t = 0; t < T_; ++t) {
            if (threadIdx.x == 0) waitc(ctr, t, 0);           // h1 slot t+1 complete
            __syncthreads();
            f32x4 acc[4];
            #pragma unroll
            for (int g = 0; g < 4; ++g) acc[g] = (f32x4){bi[g], bi[g], bi[g], bi[g]};
            gemm_k1024(h1hist + (size_t)(t + 1) * BH, ws, lm, lq, m0, acc);
            uint64_t* Qw64 = (uint64_t*)(Qhist + (size_t)t * (4 * BH));
            #pragma unroll
            for (int r = 0; r < 4; ++r) {
                int b = m0 + lq * 4 + r, j = js * 16 + lm;
                size_t base = ((size_t)b * H_ + j) * 2;
                astore64(Qw64 + base,     packf2(acc[0][r], acc[1][r]));
                astore64(Qw64 + base + 1, packf2(acc[2][r], acc[3][r]));
            }
            __syncthreads();                    // drain
            if (threadIdx.x == 0) arrive(ctr, t, 1, js);
        }
    } else {
        // ---- layer-2 recurrence: dep on role1[t] and itself[t-1] ----
        for (int t = 0; t < T_; ++t) {
            // parallel dual wait: wave0-lane0 polls Q flag, wave1-lane0 polls h2 flag
            if (threadIdx.x == 0) waitc(ctr, t, 1);           // Q slot t complete
            else if (threadIdx.x == 64 && t > 0) waitc(ctr, t - 1, 2); // h2 slot t complete
            __syncthreads();
            const uint4* Qr = (const uint4*)(Qhist + (size_t)t * (4 * BH));
            f32x4 acc[4];
            #pragma unroll
            for (int r = 0; r < 4; ++r) {
                uint4 p = Qr[(size_t)(m0 + lq * 4 + r) * H_ + js * 16 + lm];
                union { uint32_t u; float f; } x0, x1, x2, x3;
                x0.u = p.x; x1.u = p.y; x2.u = p.z; x3.u = p.w;
                acc[0][r] = x0.f; acc[1][r] = x1.f;
                acc[2][r] = x2.f; acc[3][r] = x3.f;
            }
            gemm_k1024(h2hist + (size_t)t * BH, ws, lm, lq, m0, acc);
            #pragma unroll
            for (int r = 0; r < 4; ++r) {
                if (t < q[r]) lstm_elem(acc, r, c_reg, h_reg, hb_reg);
                hstage[m0 + lq * 4 + r][lm] = hb_reg[r];
            }
            __syncthreads();
            store_h_tile(h2hist + (size_t)(t + 1) * BH, js, &hstage[0][0]);
            __syncthreads();                    // drain
            if (t < T_ - 1 && threadIdx.x == 0) arrive(ctr, t, 2, js);
        }
        #pragma unroll
        for (int r = 0; r < 4; ++r) {
            int b = m0 + lq * 4 + r, j = js * 16 + lm;
            h2f[b * H_ + j] = h_reg[r]; c2f[b * H_ + j] = c_reg[r];
        }
    }
}

// ---------------- output fan-out ----------------
__global__ void write_out(const float* __restrict__ h1f, const float* __restrict__ h2f,
                          const float* __restrict__ c1f, const float* __restrict__ c2f,
                          float* __restrict__ out) {
    const long long EQ = (long long)B_ * H_ * 784;      // 51,380,224
    const long long n4 = (EQ + 4LL * B_ * H_) / 4;      // 12,910,592
    long long i4 = (long long)blockIdx.x * blockDim.x + threadIdx.x;
    long long stride = (long long)gridDim.x * blockDim.x;
    for (; i4 < n4; i4 += stride) {
        long long f = i4 * 4;
        float4 v;
        if (f < EQ) {
            long long bh = f / 784;
            float val = h2f[bh];
            v = make_float4(val, val, val, val);
        } else {
            long long r = f - EQ;
            int which = (int)(r >> 16);
            int j = (int)(r & 65535);
            const float* src = (which == 0) ? h1f : (which == 1) ? h2f : (which == 2) ? c1f : c2f;
            v = *reinterpret_cast<const float4*>(src + j);
        }
        reinterpret_cast<float4*>(out)[i4] = v;
    }
}

// ---------------- launch ----------------
extern "C" void kernel_launch(void* const* d_in, const int* in_sizes, int n_in,
                              void* d_out, int out_size, void* d_ws, size_t ws_size,
                              hipStream_t stream) {
    const int*   questions = (const int*)d_in[0];
    const int*   qlen      = (const int*)d_in[1];
    const float* embed     = (const float*)d_in[2];
    const float* W_ih1     = (const float*)d_in[3];
    const float* W_hh1     = (const float*)d_in[4];
    const float* b_ih1     = (const float*)d_in[5];
    const float* b_hh1     = (const float*)d_in[6];
    const float* W_ih2     = (const float*)d_in[7];
    const float* W_hh2     = (const float*)d_in[8];
    const float* b_ih2     = (const float*)d_in[9];
    const float* b_hh2     = (const float*)d_in[10];
    float* out = (float*)d_out;

    char* w = (char*)d_ws;
    float*    xg     = (float*)(w + 0);                 // 33,554,432
    ushort_t* Wih1p  = (ushort_t*)(w + 33554432);       //  2,621,440
    ushort_t* Xp     = (ushort_t*)(w + 36175872);       //  1,310,720 (dead after xgemm)
    int*      ctr    = (int*)(w + 36175872);            //  overlays Xp: 49,152 B
    ushort_t* h1hist = (ushort_t*)(w + 37486592);       // 33*131,072 = 4,325,376
    ushort_t* h2hist = (ushort_t*)(w + 41811968);       // 33*131,072 = 4,325,376
    float*    Qhist  = (float*)(w + 46137344);          // 32*1,048,576 = 33,554,432
    float*    h1f    = (float*)(w + 79691776);          //    262,144
    float*    c1f    = (float*)(w + 79953920);
    float*    h2f    = (float*)(w + 80216064);
    float*    c2f    = (float*)(w + 80478208);          // end 80,740,352

    // zero initial-state slots (h1(-1), h2(-1))
    hipMemsetAsync(w + 37486592, 0, 131072, stream);
    hipMemsetAsync(w + 41811968, 0, 131072, stream);

    prep_inputs<<<3328, 256, 0, stream>>>(questions, embed, Xp, W_ih1, Wih1p);
    xgemm<<<dim3(32, 64), 256, 0, stream>>>(Xp, Wih1p, b_ih1, b_hh1, xg);

    // Xp is dead now; zero the barrier counters that overlay it (stream-ordered)
    hipMemsetAsync(w + 36175872, 0, 49152, stream);

    lstm_persist<<<NBLK, 256, 0, stream>>>(W_hh1, W_ih2, W_hh2, b_ih2, b_hh2,
                                           xg, qlen,
                                           h1hist, h2hist, Qhist,
                                           h1f, c1f, h2f, c2f, ctr);

    write_out<<<4096, 256, 0, stream>>>(h1f, h2f, c1f, c2f, out);
}

// Round 7
// 631.918 us; speedup vs baseline: 1.0059x; 1.0059x over previous
//
#include <hip/hip_runtime.h>
#include <hip/hip_bf16.h>
#include <cstdint>

#define B_  64
#define T_  32
#define E_  300
#define EP  320      // padded K for the x-precompute GEMM
#define H_  1024
#define G4  4096     // 4*H
#define BH  65536    // B_*H_
#define NBLK 192     // persistent blocks: 64 L1 + 64 I2 + 64 H2

typedef __attribute__((ext_vector_type(8))) short bf16x8;
typedef __attribute__((ext_vector_type(4))) float f32x4;
typedef unsigned short ushort_t;

__device__ __forceinline__ bf16x8 load_b8(const ushort_t* p) {
    union { uint4 u; bf16x8 v; } c;
    c.u = *reinterpret_cast<const uint4*>(p);
    return c.v;
}

__device__ __forceinline__ ushort_t f2bf(float x) {
    union { float f; uint32_t u; } c; c.f = x;
    uint32_t r = c.u + 0x7fffu + ((c.u >> 16) & 1u);   // RNE
    return (ushort_t)(r >> 16);
}

__device__ __forceinline__ float sigm(float x) { return 1.0f / (1.0f + __expf(-x)); }

// agent-scope (cross-XCD write-through) stores for produced data; plain loads
// are used on the consumer side (unique buffer per timestep => no stale lines)
__device__ __forceinline__ void astore64(uint64_t* p, uint64_t v) {
    __hip_atomic_store(p, v, __ATOMIC_RELAXED, __HIP_MEMORY_SCOPE_AGENT);
}
__device__ __forceinline__ uint64_t packf2(float a, float b) {
    union { float f[2]; uint64_t u; } c; c.f[0] = a; c.f[1] = b; return c.u;
}

// ---- contention-free dataflow flags ----
// one int per (role, block), each on its OWN 64B line (no false sharing, no RMW):
// producer: plain agent-scope store of monotonically-increasing step count.
// waiter: one full wave; lane l polls block l's flag; __all() joins.
// DIAGNOSTIC spin guard: legitimate waits are <20us; if the protocol ever
// wedges, exit after ~2^22 polls (hundreds of ms) so the kernel COMPLETES
// with wrong outputs (passed:false) instead of hanging the container.
__device__ __forceinline__ void setflag(int* flags, int role, int js, int val) {
    __hip_atomic_store(&flags[(role * 64 + js) * 16], val,
                       __ATOMIC_RELAXED, __HIP_MEMORY_SCOPE_AGENT);
}
__device__ __forceinline__ void waitwave(const int* flags, int role, int target, int lane) {
    const int* p = &flags[(role * 64 + lane) * 16];
    int guard = 0;
    for (;;) {
        int v = __hip_atomic_load(p, __ATOMIC_RELAXED, __HIP_MEMORY_SCOPE_AGENT);
        if (__all(v >= target)) return;
        if (++guard > (1 << 22)) return;        // diagnostic bail-out (never hit when healthy)
        __builtin_amdgcn_s_sleep(1);
    }
}

// ---------------- fused prep kernel ----------------
// blocks [0,1280): embed gather+pad ; [1280,3328): W_ih1 pad+convert
__global__ void prep_inputs(const int* __restrict__ q, const float* __restrict__ table,
                            ushort_t* __restrict__ Xp,
                            const float* __restrict__ Wsrc, ushort_t* __restrict__ Wdst) {
    int blk = blockIdx.x;
    if (blk < 1280) {
        int i = blk * 256 + threadIdx.x;
        const int n = B_ * T_ * EP;
        for (; i < n; i += 1280 * 256) {
            int r = i / EP, c = i - r * EP;
            Xp[i] = (c < E_) ? f2bf(table[q[r] * E_ + c]) : (ushort_t)0;
        }
    } else {
        int i = (blk - 1280) * 256 + threadIdx.x;
        const int n = G4 * EP;
        for (; i < n; i += 2048 * 256) {
            int r = i / EP, c = i - r * EP;
            Wdst[i] = (c < E_) ? f2bf(Wsrc[r * E_ + c]) : (ushort_t)0;
        }
    }
}

// ---------------- x-part precompute GEMM ----------------
// xg[t][b][4H] = Xp @ Wih1p^T + (b_ih1+b_hh1)
__launch_bounds__(256)
__global__ void xgemm(const ushort_t* __restrict__ Xp, const ushort_t* __restrict__ Wp,
                      const float* __restrict__ b_ih1, const float* __restrict__ b_hh1,
                      float* __restrict__ xg) {
    int mblk = blockIdx.x, nblk = blockIdx.y;
    int wave = threadIdx.x >> 6, lane = threadIdx.x & 63;
    int lm = lane & 15, lq = lane >> 4;
    int m0 = mblk * 64 + wave * 16;
    f32x4 acc[4];
    #pragma unroll
    for (int g = 0; g < 4; ++g) {
        int n = nblk * 64 + g * 16 + lm;
        float bv = b_ih1[n] + b_hh1[n];
        acc[g] = (f32x4){bv, bv, bv, bv};
    }
    for (int k0 = 0; k0 < EP; k0 += 32) {
        bf16x8 a = load_b8(Xp + (m0 + lm) * EP + k0 + lq * 8);
        #pragma unroll
        for (int g = 0; g < 4; ++g) {
            bf16x8 b = load_b8(Wp + (nblk * 64 + g * 16 + lm) * EP + k0 + lq * 8);
            acc[g] = __builtin_amdgcn_mfma_f32_16x16x32_bf16(a, b, acc[g], 0, 0, 0);
        }
    }
    #pragma unroll
    for (int g = 0; g < 4; ++g)
        #pragma unroll
        for (int r = 0; r < 4; ++r) {
            int m = m0 + lq * 4 + r;          // m = b*T + t
            int b = m >> 5, t = m & 31;
            int n = nblk * 64 + g * 16 + lm;
            xg[((size_t)t * B_ + b) * G4 + n] = acc[g][r];
        }
}

// ---------------- persistent recurrence kernel ----------------
// blocks 0-63: L1 (Whh1), 64-127: I2 (Wih2), 128-191: H2 (Whh2)

// full-depth prefetch: all 32 uint4 h-loads in flight (132KB LDS caps us at
// 1 block/CU -> 1 wave/SIMD -> large VGPR budget without occupancy cost)
__device__ __forceinline__ void gemm_k1024(const ushort_t* __restrict__ hvec,
                                           const ushort_t (*w)[1032],
                                           int lm, int lq, int m0, f32x4 acc[4]) {
    const uint4* hr = reinterpret_cast<const uint4*>(hvec + (size_t)(m0 + lm) * H_);
    uint4 buf[32];
    #pragma unroll
    for (int grp = 0; grp < 4; ++grp)
        #pragma unroll
        for (int i = 0; i < 8; ++i)
            buf[grp * 8 + i] = hr[grp * 32 + i * 4 + lq];
    #pragma unroll
    for (int grp = 0; grp < 4; ++grp)
        #pragma unroll
        for (int i = 0; i < 8; ++i) {
            int k0 = grp * 256 + i * 32;
            union { uint4 u; bf16x8 v; } a; a.u = buf[grp * 8 + i];
            #pragma unroll
            for (int g = 0; g < 4; ++g) {
                bf16x8 bb = load_b8(&w[g * 16 + lm][k0 + lq * 8]);
                acc[g] = __builtin_amdgcn_mfma_f32_16x16x32_bf16(a.v, bb, acc[g], 0, 0, 0);
            }
        }
}

__device__ __forceinline__ void lstm_elem(const f32x4 acc[4], int r,
                                          float* c, float* h, ushort_t* hb) {
    float iv = sigm(acc[0][r]);
    float fv = sigm(acc[1][r]);
    float gv = tanhf(acc[2][r]);
    float ov = sigm(acc[3][r]);
    float cn = fv * c[r] + iv * gv;
    float hv = ov * tanhf(cn);
    c[r] = cn; h[r] = hv; hb[r] = f2bf(hv);
}

// repacked h-tile store: 256 coalesced 8-byte agent stores (was 1024 x 2B)
__device__ __forceinline__ void store_h_tile(ushort_t* dst, int js, const ushort_t* hst) {
    int tid = threadIdx.x;
    uint64_t v = reinterpret_cast<const uint64_t*>(hst)[tid];
    astore64(reinterpret_cast<uint64_t*>(dst + (size_t)(tid >> 2) * H_ + js * 16) + (tid & 3), v);
}

__global__ __launch_bounds__(256) void lstm_persist(
    const float* __restrict__ Whh1, const float* __restrict__ Wih2,
    const float* __restrict__ Whh2,
    const float* __restrict__ b_ih2, const float* __restrict__ b_hh2,
    const float* __restrict__ xg, const int* __restrict__ qlen,
    ushort_t* __restrict__ h1hist,   // 33 slots of BH bf16; slot k = h1(k-1)
    ushort_t* __restrict__ h2hist,   // 33 slots of BH bf16; slot k = h2(k-1)
    float* __restrict__ Qhist,       // 32 slots of BH*4 fp32, gate-interleaved [b][j][4]
    float* __restrict__ h1f, float* __restrict__ c1f,
    float* __restrict__ h2f, float* __restrict__ c2f,
    int* __restrict__ flags)
{
    __shared__ ushort_t ws[64][1032];              // 132,096 B
    __shared__ __align__(16) ushort_t hstage[64][16];  // 2,048 B -> still 1 block/CU

    const int blk  = blockIdx.x;
    const int role = blk >> 6;          // 0=L1, 1=I2, 2=H2
    const int js   = blk & 63;
    const int wave = threadIdx.x >> 6, lane = threadIdx.x & 63;
    const int lm = lane & 15, lq = lane >> 4;
    const int m0 = wave * 16;

    // ---- stage weight slice fp32 -> bf16 into LDS (once) ----
    const float* Wsrc = (role == 0) ? Whh1 : (role == 1) ? Wih2 : Whh2;
    for (int idx = threadIdx.x; idx < 64 * 256; idx += 256) {
        int r = idx >> 8, c4 = idx & 255;
        int grow = (r >> 4) * H_ + js * 16 + (r & 15);
        float4 v = reinterpret_cast<const float4*>(Wsrc + (size_t)grow * H_)[c4];
        uint2 pk;
        pk.x = (uint32_t)f2bf(v.x) | ((uint32_t)f2bf(v.y) << 16);
        pk.y = (uint32_t)f2bf(v.z) | ((uint32_t)f2bf(v.w) << 16);
        *reinterpret_cast<uint2*>(&ws[r][c4 * 4]) = pk;
    }
    __syncthreads();

    int q[4];
    #pragma unroll
    for (int r = 0; r < 4; ++r) q[r] = qlen[m0 + lq * 4 + r];

    float    c_reg[4]  = {0.f, 0.f, 0.f, 0.f};
    float    h_reg[4]  = {0.f, 0.f, 0.f, 0.f};
    ushort_t hb_reg[4] = {0, 0, 0, 0};

    if (role == 0) {
        // ---- layer-1 recurrence: dep only on itself (64-block group) ----
        for (int t = 0; t < T_; ++t) {
            f32x4 acc[4];                       // xg loads issue before the wait
            #pragma unroll
            for (int g = 0; g < 4; ++g)
                #pragma unroll
                for (int r = 0; r < 4; ++r)
                    acc[g][r] = xg[((size_t)t * B_ + (m0 + lq * 4 + r)) * G4 + g * H_ + js * 16 + lm];
            if (t > 0) {
                if (wave == 0) waitwave(flags, 0, t, lane);   // h1 slot t complete
                __syncthreads();
            }
            gemm_k1024(h1hist + (size_t)t * BH, ws, lm, lq, m0, acc);
            #pragma unroll
            for (int r = 0; r < 4; ++r) {
                if (t < q[r]) lstm_elem(acc, r, c_reg, h_reg, hb_reg);
                hstage[m0 + lq * 4 + r][lm] = hb_reg[r];
            }
            __syncthreads();
            store_h_tile(h1hist + (size_t)(t + 1) * BH, js, &hstage[0][0]);
            __syncthreads();                    // drains vmcnt(0): stores visible at L3
            if (threadIdx.x == 0) setflag(flags, 0, js, t + 1);
        }
        #pragma unroll
        for (int r = 0; r < 4; ++r) {
            int b = m0 + lq * 4 + r, j = js * 16 + lm;
            h1f[b * H_ + j] = h_reg[r]; c1f[b * H_ + j] = c_reg[r];
        }
    } else if (role == 1) {
        // ---- Q(t) = Wih2 . h1(t) + bias2 : dep only on role0[t] ----
        float bi[4];
        #pragma unroll
        for (int g = 0; g < 4; ++g) {
            int n = g * H_ + js * 16 + lm;
            bi[g] = b_ih2[n] + b_hh2[n];
        }
        for (int t = 0; t < T_; ++t) {
            if (wave == 0) waitwave(flags, 0, t + 1, lane);   // h1 slot t+1 complete
            __syncthreads();
            f32x4 acc[4];
            #pragma unroll
            for (int g = 0; g < 4; ++g) acc[g] = (f32x4){bi[g], bi[g], bi[g], bi[g]};
            gemm_k1024(h1hist + (size_t)(t + 1) * BH, ws, lm, lq, m0, acc);
            uint64_t* Qw64 = (uint64_t*)(Qhist + (size_t)t * (4 * BH));
            #pragma unroll
            for (int r = 0; r < 4; ++r) {
                int b = m0 + lq * 4 + r, j = js * 16 + lm;
                size_t base = ((size_t)b * H_ + j) * 2;
                astore64(Qw64 + base,     packf2(acc[0][r], acc[1][r]));
                astore64(Qw64 + base + 1, packf2(acc[2][r], acc[3][r]));
            }
            __syncthreads();                    // drain
            if (threadIdx.x == 0) setflag(flags, 1, js, t + 1);
        }
    } else {
        // ---- layer-2 recurrence: dep on role1[t] and itself[t-1] ----
        for (int t = 0; t < T_; ++t) {
            // parallel dual wait: wave0 polls Q flags, wave1 polls own h2 flags
            if (t > 0) {
                if (wave == 0)      waitwave(flags, 1, t + 1, lane);  // Q slot t done
                else if (wave == 1) waitwave(flags, 2, t,     lane);  // h2 slot t done
            } else {
                if (wave == 0)      waitwave(flags, 1, 1,     lane);
            }
            __syncthreads();
            // issue Q loads now; they complete under the GEMM below
            const uint4* Qr = (const uint4*)(Qhist + (size_t)t * (4 * BH));
            uint4 qp[4];
            #pragma unroll
            for (int r = 0; r < 4; ++r)
                qp[r] = Qr[(size_t)(m0 + lq * 4 + r) * H_ + js * 16 + lm];
            f32x4 acc[4];
            #pragma unroll
            for (int g = 0; g < 4; ++g) acc[g] = (f32x4){0.f, 0.f, 0.f, 0.f};
            gemm_k1024(h2hist + (size_t)t * BH, ws, lm, lq, m0, acc);
            #pragma unroll
            for (int r = 0; r < 4; ++r) {
                union { uint32_t u; float f; } x0, x1, x2, x3;
                x0.u = qp[r].x; x1.u = qp[r].y; x2.u = qp[r].z; x3.u = qp[r].w;
                acc[0][r] += x0.f; acc[1][r] += x1.f;
                acc[2][r] += x2.f; acc[3][r] += x3.f;
            }
            #pragma unroll
            for (int r = 0; r < 4; ++r) {
                if (t < q[r]) lstm_elem(acc, r, c_reg, h_reg, hb_reg);
                hstage[m0 + lq * 4 + r][lm] = hb_reg[r];
            }
            __syncthreads();
            store_h_tile(h2hist + (size_t)(t + 1) * BH, js, &hstage[0][0]);
            __syncthreads();                    // drain
            if (t < T_ - 1 && threadIdx.x == 0) setflag(flags, 2, js, t + 1);
        }
        #pragma unroll
        for (int r = 0; r < 4; ++r) {
            int b = m0 + lq * 4 + r, j = js * 16 + lm;
            h2f[b * H_ + j] = h_reg[r]; c2f[b * H_ + j] = c_reg[r];
        }
    }
}

// ---------------- output fan-out ----------------
__global__ void write_out(const float* __restrict__ h1f, const float* __restrict__ h2f,
                          const float* __restrict__ c1f, const float* __restrict__ c2f,
                          float* __restrict__ out) {
    const long long EQ = (long long)B_ * H_ * 784;      // 51,380,224
    const long long n4 = (EQ + 4LL * B_ * H_) / 4;      // 12,910,592
    long long i4 = (long long)blockIdx.x * blockDim.x + threadIdx.x;
    long long stride = (long long)gridDim.x * blockDim.x;
    for (; i4 < n4; i4 += stride) {
        long long f = i4 * 4;
        float4 v;
        if (f < EQ) {
            long long bh = f / 784;
            float val = h2f[bh];
            v = make_float4(val, val, val, val);
        } else {
            long long r = f - EQ;
            int which = (int)(r >> 16);
            int j = (int)(r & 65535);
            const float* src = (which == 0) ? h1f : (which == 1) ? h2f : (which == 2) ? c1f : c2f;
            v = *reinterpret_cast<const float4*>(src + j);
        }
        reinterpret_cast<float4*>(out)[i4] = v;
    }
}

// ---------------- launch ----------------
extern "C" void kernel_launch(void* const* d_in, const int* in_sizes, int n_in,
                              void* d_out, int out_size, void* d_ws, size_t ws_size,
                              hipStream_t stream) {
    const int*   questions = (const int*)d_in[0];
    const int*   qlen      = (const int*)d_in[1];
    const float* embed     = (const float*)d_in[2];
    const float* W_ih1     = (const float*)d_in[3];
    const float* W_hh1     = (const float*)d_in[4];
    const float* b_ih1     = (const float*)d_in[5];
    const float* b_hh1     = (const float*)d_in[6];
    const float* W_ih2     = (const float*)d_in[7];
    const float* W_hh2     = (const float*)d_in[8];
    const float* b_ih2     = (const float*)d_in[9];
    const float* b_hh2     = (const float*)d_in[10];
    float* out = (float*)d_out;

    char* w = (char*)d_ws;
    float*    xg     = (float*)(w + 0);                 // 33,554,432
    ushort_t* Wih1p  = (ushort_t*)(w + 33554432);       //  2,621,440
    ushort_t* Xp     = (ushort_t*)(w + 36175872);       //  1,310,720 (dead after xgemm)
    int*      flags  = (int*)(w + 36175872);            //  overlays Xp: 3*64*64B = 12,288
    ushort_t* h1hist = (ushort_t*)(w + 37486592);       // 33*131,072 = 4,325,376
    ushort_t* h2hist = (ushort_t*)(w + 41811968);       // 33*131,072 = 4,325,376
    float*    Qhist  = (float*)(w + 46137344);          // 32*1,048,576 = 33,554,432
    float*    h1f    = (float*)(w + 79691776);          //    262,144
    float*    c1f    = (float*)(w + 79953920);
    float*    h2f    = (float*)(w + 80216064);
    float*    c2f    = (float*)(w + 80478208);          // end 80,740,352

    // zero initial-state slots (h1(-1), h2(-1))
    hipMemsetAsync(w + 37486592, 0, 131072, stream);
    hipMemsetAsync(w + 41811968, 0, 131072, stream);

    prep_inputs<<<3328, 256, 0, stream>>>(questions, embed, Xp, W_ih1, Wih1p);
    xgemm<<<dim3(32, 64), 256, 0, stream>>>(Xp, Wih1p, b_ih1, b_hh1, xg);

    // Xp is dead now; zero the flag region that overlays it (stream-ordered)
    hipMemsetAsync(w + 36175872, 0, 12288, stream);

    lstm_persist<<<NBLK, 256, 0, stream>>>(W_hh1, W_ih2, W_hh2, b_ih2, b_hh2,
                                           xg, qlen,
                                           h1hist, h2hist, Qhist,
                                           h1f, c1f, h2f, c2f, flags);

    write_out<<<4096, 256, 0, stream>>>(h1f, h2f, c1f, c2f, out);
}

// Round 8
// 619.225 us; speedup vs baseline: 1.0266x; 1.0205x over previous
//
#include <hip/hip_runtime.h>
#include <hip/hip_bf16.h>
#include <cstdint>

#define B_  64
#define T_  32
#define E_  300
#define EP  320      // padded K for the x-precompute GEMM
#define H_  1024
#define G4  4096     // 4*H
#define BH  65536    // B_*H_
#define NBLK 192     // persistent blocks: 64 L1 + 64 I2 + 64 H2

typedef __attribute__((ext_vector_type(8))) short bf16x8;
typedef __attribute__((ext_vector_type(4))) float f32x4;
typedef unsigned short ushort_t;

__device__ __forceinline__ bf16x8 load_b8(const ushort_t* p) {
    union { uint4 u; bf16x8 v; } c;
    c.u = *reinterpret_cast<const uint4*>(p);
    return c.v;
}

__device__ __forceinline__ ushort_t f2bf(float x) {
    union { float f; uint32_t u; } c; c.f = x;
    uint32_t r = c.u + 0x7fffu + ((c.u >> 16) & 1u);   // RNE
    return (ushort_t)(r >> 16);
}

__device__ __forceinline__ float sigm(float x) { return 1.0f / (1.0f + __expf(-x)); }

// agent-scope (cross-XCD write-through) stores for produced data; plain loads
// are used on the consumer side (unique buffer per timestep + dispatch-boundary
// invalidate => no stale lines)
__device__ __forceinline__ void astore64(uint64_t* p, uint64_t v) {
    __hip_atomic_store(p, v, __ATOMIC_RELAXED, __HIP_MEMORY_SCOPE_AGENT);
}
__device__ __forceinline__ uint64_t packf2(float a, float b) {
    union { float f[2]; uint64_t u; } c; c.f[0] = a; c.f[1] = b; return c.u;
}

// ---- contention-free dataflow flags (proven neutral vs atomics; kept) ----
__device__ __forceinline__ void setflag(int* flags, int role, int js, int val) {
    __hip_atomic_store(&flags[(role * 64 + js) * 16], val,
                       __ATOMIC_RELAXED, __HIP_MEMORY_SCOPE_AGENT);
}
__device__ __forceinline__ void waitwave(const int* flags, int role, int target, int lane) {
    const int* p = &flags[(role * 64 + lane) * 16];
    int guard = 0;
    for (;;) {
        int v = __hip_atomic_load(p, __ATOMIC_RELAXED, __HIP_MEMORY_SCOPE_AGENT);
        if (__all(v >= target)) return;
        if (++guard > (1 << 22)) return;        // diagnostic bail-out (never hit when healthy)
        __builtin_amdgcn_s_sleep(1);
    }
}

// ---------------- fused prep kernel ----------------
__global__ void prep_inputs(const int* __restrict__ q, const float* __restrict__ table,
                            ushort_t* __restrict__ Xp,
                            const float* __restrict__ Wsrc, ushort_t* __restrict__ Wdst) {
    int blk = blockIdx.x;
    if (blk < 1280) {
        int i = blk * 256 + threadIdx.x;
        const int n = B_ * T_ * EP;
        for (; i < n; i += 1280 * 256) {
            int r = i / EP, c = i - r * EP;
            Xp[i] = (c < E_) ? f2bf(table[q[r] * E_ + c]) : (ushort_t)0;
        }
    } else {
        int i = (blk - 1280) * 256 + threadIdx.x;
        const int n = G4 * EP;
        for (; i < n; i += 2048 * 256) {
            int r = i / EP, c = i - r * EP;
            Wdst[i] = (c < E_) ? f2bf(Wsrc[r * E_ + c]) : (ushort_t)0;
        }
    }
}

// ---------------- x-part precompute GEMM ----------------
// NEW layout: xg[t][b][j][4gates] fp32 (gate-interleaved, like Qhist) so the
// role-0 consumer reads ONE uint4 per (b,j) instead of 16 scattered 4B loads.
__launch_bounds__(256)
__global__ void xgemm(const ushort_t* __restrict__ Xp, const ushort_t* __restrict__ Wp,
                      const float* __restrict__ b_ih1, const float* __restrict__ b_hh1,
                      float* __restrict__ xg) {
    int mblk = blockIdx.x, nblk = blockIdx.y;
    int wave = threadIdx.x >> 6, lane = threadIdx.x & 63;
    int lm = lane & 15, lq = lane >> 4;
    int m0 = mblk * 64 + wave * 16;
    f32x4 acc[4];
    #pragma unroll
    for (int g = 0; g < 4; ++g) {
        int n = nblk * 64 + g * 16 + lm;
        float bv = b_ih1[n] + b_hh1[n];
        acc[g] = (f32x4){bv, bv, bv, bv};
    }
    for (int k0 = 0; k0 < EP; k0 += 32) {
        bf16x8 a = load_b8(Xp + (m0 + lm) * EP + k0 + lq * 8);
        #pragma unroll
        for (int g = 0; g < 4; ++g) {
            bf16x8 b = load_b8(Wp + (nblk * 64 + g * 16 + lm) * EP + k0 + lq * 8);
            acc[g] = __builtin_amdgcn_mfma_f32_16x16x32_bf16(a, b, acc[g], 0, 0, 0);
        }
    }
    #pragma unroll
    for (int g = 0; g < 4; ++g)
        #pragma unroll
        for (int r = 0; r < 4; ++r) {
            int m = m0 + lq * 4 + r;          // m = b*T + t
            int b = m >> 5, t = m & 31;
            int n = nblk * 64 + g * 16 + lm;  // raw 4H index
            int gate = n >> 10, j = n & 1023;
            xg[(((size_t)t * B_ + b) * H_ + j) * 4 + gate] = acc[g][r];
        }
}

// ---------------- persistent recurrence kernel ----------------
// blocks 0-63: L1 (Whh1), 64-127: I2 (Wih2), 128-191: H2 (Whh2)
//
// h-history layout is COLUMN-MAJOR BY BLOCK: slot[cb][b][16cols] bf16, so the
// producing block writes ONE contiguous full-line 2KB burst and consumers read
// 512B-contiguous chunks per load instruction (was 32B half-lines / 64B segs).

// LDS weight tile: [64 rows][1024 cols] bf16, XOR-swizzled (T2):
//   byte_off_in_row ^= (row&7)<<4   -> ds_read_b128 at the 8-clock BW floor.
__device__ __forceinline__ void gemm_cm(const ushort_t* __restrict__ hslot,
                                        const ushort_t* __restrict__ wsf,
                                        int lm, int lq, int m0, f32x4 acc[4]) {
    const uint4* hr = reinterpret_cast<const uint4*>(hslot);
    const int rbase = (m0 + lm) * 2 + (lq & 1);
    const int cbo = lq >> 1;
    uint4 buf[32];
    #pragma unroll
    for (int grp = 0; grp < 4; ++grp)
        #pragma unroll
        for (int i = 0; i < 8; ++i)
            buf[grp * 8 + i] = hr[(grp * 16 + i * 2 + cbo) * 128 + rbase];
    #pragma unroll
    for (int grp = 0; grp < 4; ++grp)
        #pragma unroll
        for (int i = 0; i < 8; ++i) {
            int k0 = grp * 256 + i * 32;
            union { uint4 u; bf16x8 v; } a; a.u = buf[grp * 8 + i];
            #pragma unroll
            for (int g = 0; g < 4; ++g) {
                int row = g * 16 + lm;
                bf16x8 bb = load_b8(wsf + row * 1024 + ((k0 + lq * 8) ^ ((lm & 7) << 3)));
                acc[g] = __builtin_amdgcn_mfma_f32_16x16x32_bf16(a.v, bb, acc[g], 0, 0, 0);
            }
        }
}

__device__ __forceinline__ void lstm_elem(const f32x4 acc[4], int r,
                                          float* c, float* h, ushort_t* hb) {
    float iv = sigm(acc[0][r]);
    float fv = sigm(acc[1][r]);
    float gv = tanhf(acc[2][r]);
    float ov = sigm(acc[3][r]);
    float cn = fv * c[r] + iv * gv;
    float hv = ov * tanhf(cn);
    c[r] = cn; h[r] = hv; hb[r] = f2bf(hv);
}

// col-major h-tile store: ONE contiguous 2KB full-line burst per block
__device__ __forceinline__ void store_h_tile(ushort_t* slot, int js, const ushort_t* hst) {
    int tid = threadIdx.x;
    uint64_t v = reinterpret_cast<const uint64_t*>(hst)[tid];
    astore64(reinterpret_cast<uint64_t*>(slot) + js * 256 + tid, v);
}

__global__ __launch_bounds__(256) void lstm_persist(
    const float* __restrict__ Whh1, const float* __restrict__ Wih2,
    const float* __restrict__ Whh2,
    const float* __restrict__ b_ih2, const float* __restrict__ b_hh2,
    const float* __restrict__ xg, const int* __restrict__ qlen,
    ushort_t* __restrict__ h1hist,   // 33 slots of BH bf16, col-major; slot k = h1(k-1)
    ushort_t* __restrict__ h2hist,   // 33 slots of BH bf16, col-major; slot k = h2(k-1)
    float* __restrict__ Qhist,       // 32 slots of BH*4 fp32, gate-interleaved [b][j][4]
    float* __restrict__ h1f, float* __restrict__ c1f,
    float* __restrict__ h2f, float* __restrict__ c2f,
    int* __restrict__ flags)
{
    __shared__ ushort_t ws[64 * 1024];             // 131,072 B (swizzled, unpadded)
    __shared__ __align__(16) ushort_t hstage[64][16];  // 2,048 B -> 1 block/CU

    const int blk  = blockIdx.x;
    const int role = blk >> 6;          // 0=L1, 1=I2, 2=H2
    const int js   = blk & 63;
    const int wave = threadIdx.x >> 6, lane = threadIdx.x & 63;
    const int lm = lane & 15, lq = lane >> 4;
    const int m0 = wave * 16;

    // ---- stage weight slice fp32 -> bf16 into LDS (once, swizzled) ----
    const float* Wsrc = (role == 0) ? Whh1 : (role == 1) ? Wih2 : Whh2;
    uint2* wsp = reinterpret_cast<uint2*>(ws);
    for (int idx = threadIdx.x; idx < 64 * 256; idx += 256) {
        int r = idx >> 8, c4 = idx & 255;
        int grow = (r >> 4) * H_ + js * 16 + (r & 15);
        float4 v = reinterpret_cast<const float4*>(Wsrc + (size_t)grow * H_)[c4];
        uint2 pk;
        pk.x = (uint32_t)f2bf(v.x) | ((uint32_t)f2bf(v.y) << 16);
        pk.y = (uint32_t)f2bf(v.z) | ((uint32_t)f2bf(v.w) << 16);
        wsp[r * 256 + (c4 ^ ((r & 7) << 1))] = pk;   // 8B-unit XOR == byte^((r&7)<<4)
    }
    __syncthreads();

    int q[4];
    #pragma unroll
    for (int r = 0; r < 4; ++r) q[r] = qlen[m0 + lq * 4 + r];

    float    c_reg[4]  = {0.f, 0.f, 0.f, 0.f};
    float    h_reg[4]  = {0.f, 0.f, 0.f, 0.f};
    ushort_t hb_reg[4] = {0, 0, 0, 0};

    if (role == 0) {
        // ---- layer-1 recurrence: dep only on itself (64-block group) ----
        for (int t = 0; t < T_; ++t) {
            uint4 xq[4];                        // xg loads issue before the wait
            #pragma unroll
            for (int r = 0; r < 4; ++r)
                xq[r] = reinterpret_cast<const uint4*>(xg)
                        [((size_t)t * B_ + (m0 + lq * 4 + r)) * H_ + js * 16 + lm];
            if (t > 0) {
                if (wave == 0) waitwave(flags, 0, t, lane);   // h1 slot t complete
                __syncthreads();
            }
            f32x4 acc[4];
            #pragma unroll
            for (int r = 0; r < 4; ++r) {
                union { uint32_t u; float f; } x0, x1, x2, x3;
                x0.u = xq[r].x; x1.u = xq[r].y; x2.u = xq[r].z; x3.u = xq[r].w;
                acc[0][r] = x0.f; acc[1][r] = x1.f;
                acc[2][r] = x2.f; acc[3][r] = x3.f;
            }
            gemm_cm(h1hist + (size_t)t * BH, ws, lm, lq, m0, acc);
            #pragma unroll
            for (int r = 0; r < 4; ++r) {
                if (t < q[r]) lstm_elem(acc, r, c_reg, h_reg, hb_reg);
                hstage[m0 + lq * 4 + r][lm] = hb_reg[r];
            }
            __syncthreads();
            store_h_tile(h1hist + (size_t)(t + 1) * BH, js, &hstage[0][0]);
            __syncthreads();                    // drains vmcnt(0): stores visible
            if (threadIdx.x == 0) setflag(flags, 0, js, t + 1);
        }
        #pragma unroll
        for (int r = 0; r < 4; ++r) {
            int b = m0 + lq * 4 + r, j = js * 16 + lm;
            h1f[b * H_ + j] = h_reg[r]; c1f[b * H_ + j] = c_reg[r];
        }
    } else if (role == 1) {
        // ---- Q(t) = Wih2 . h1(t) + bias2 : dep only on role0[t] ----
        float bi[4];
        #pragma unroll
        for (int g = 0; g < 4; ++g) {
            int n = g * H_ + js * 16 + lm;
            bi[g] = b_ih2[n] + b_hh2[n];
        }
        for (int t = 0; t < T_; ++t) {
            if (wave == 0) waitwave(flags, 0, t + 1, lane);   // h1 slot t+1 complete
            __syncthreads();
            f32x4 acc[4];
            #pragma unroll
            for (int g = 0; g < 4; ++g) acc[g] = (f32x4){bi[g], bi[g], bi[g], bi[g]};
            gemm_cm(h1hist + (size_t)(t + 1) * BH, ws, lm, lq, m0, acc);
            uint64_t* Qw64 = (uint64_t*)(Qhist + (size_t)t * (4 * BH));
            #pragma unroll
            for (int r = 0; r < 4; ++r) {
                int b = m0 + lq * 4 + r, j = js * 16 + lm;
                size_t base = ((size_t)b * H_ + j) * 2;
                astore64(Qw64 + base,     packf2(acc[0][r], acc[1][r]));
                astore64(Qw64 + base + 1, packf2(acc[2][r], acc[3][r]));
            }
            __syncthreads();                    // drain
            if (threadIdx.x == 0) setflag(flags, 1, js, t + 1);
        }
    } else {
        // ---- layer-2 recurrence: dep on role1[t] and itself[t-1] ----
        for (int t = 0; t < T_; ++t) {
            if (t > 0) {
                if (wave == 0)      waitwave(flags, 1, t + 1, lane);  // Q slot t done
                else if (wave == 1) waitwave(flags, 2, t,     lane);  // h2 slot t done
            } else {
                if (wave == 0)      waitwave(flags, 1, 1,     lane);
            }
            __syncthreads();
            // issue Q loads now; they complete under the GEMM below
            const uint4* Qr = (const uint4*)(Qhist + (size_t)t * (4 * BH));
            uint4 qp[4];
            #pragma unroll
            for (int r = 0; r < 4; ++r)
                qp[r] = Qr[(size_t)(m0 + lq * 4 + r) * H_ + js * 16 + lm];
            f32x4 acc[4];
            #pragma unroll
            for (int g = 0; g < 4; ++g) acc[g] = (f32x4){0.f, 0.f, 0.f, 0.f};
            gemm_cm(h2hist + (size_t)t * BH, ws, lm, lq, m0, acc);
            #pragma unroll
            for (int r = 0; r < 4; ++r) {
                union { uint32_t u; float f; } x0, x1, x2, x3;
                x0.u = qp[r].x; x1.u = qp[r].y; x2.u = qp[r].z; x3.u = qp[r].w;
                acc[0][r] += x0.f; acc[1][r] += x1.f;
                acc[2][r] += x2.f; acc[3][r] += x3.f;
            }
            #pragma unroll
            for (int r = 0; r < 4; ++r) {
                if (t < q[r]) lstm_elem(acc, r, c_reg, h_reg, hb_reg);
                hstage[m0 + lq * 4 + r][lm] = hb_reg[r];
            }
            __syncthreads();
            store_h_tile(h2hist + (size_t)(t + 1) * BH, js, &hstage[0][0]);
            __syncthreads();                    // drain
            if (t < T_ - 1 && threadIdx.x == 0) setflag(flags, 2, js, t + 1);
        }
        #pragma unroll
        for (int r = 0; r < 4; ++r) {
            int b = m0 + lq * 4 + r, j = js * 16 + lm;
            h2f[b * H_ + j] = h_reg[r]; c2f[b * H_ + j] = c_reg[r];
        }
    }
}

// ---------------- output fan-out ----------------
__global__ void write_out(const float* __restrict__ h1f, const float* __restrict__ h2f,
                          const float* __restrict__ c1f, const float* __restrict__ c2f,
                          float* __restrict__ out) {
    const long long EQ = (long long)B_ * H_ * 784;      // 51,380,224
    const long long n4 = (EQ + 4LL * B_ * H_) / 4;      // 12,910,592
    long long i4 = (long long)blockIdx.x * blockDim.x + threadIdx.x;
    long long stride = (long long)gridDim.x * blockDim.x;
    for (; i4 < n4; i4 += stride) {
        long long f = i4 * 4;
        float4 v;
        if (f < EQ) {
            long long bh = f / 784;
            float val = h2f[bh];
            v = make_float4(val, val, val, val);
        } else {
            long long r = f - EQ;
            int which = (int)(r >> 16);
            int j = (int)(r & 65535);
            const float* src = (which == 0) ? h1f : (which == 1) ? h2f : (which == 2) ? c1f : c2f;
            v = *reinterpret_cast<const float4*>(src + j);
        }
        reinterpret_cast<float4*>(out)[i4] = v;
    }
}

// ---------------- launch ----------------
extern "C" void kernel_launch(void* const* d_in, const int* in_sizes, int n_in,
                              void* d_out, int out_size, void* d_ws, size_t ws_size,
                              hipStream_t stream) {
    const int*   questions = (const int*)d_in[0];
    const int*   qlen      = (const int*)d_in[1];
    const float* embed     = (const float*)d_in[2];
    const float* W_ih1     = (const float*)d_in[3];
    const float* W_hh1     = (const float*)d_in[4];
    const float* b_ih1     = (const float*)d_in[5];
    const float* b_hh1     = (const float*)d_in[6];
    const float* W_ih2     = (const float*)d_in[7];
    const float* W_hh2     = (const float*)d_in[8];
    const float* b_ih2     = (const float*)d_in[9];
    const float* b_hh2     = (const float*)d_in[10];
    float* out = (float*)d_out;

    char* w = (char*)d_ws;
    float*    xg     = (float*)(w + 0);                 // 33,554,432
    ushort_t* Wih1p  = (ushort_t*)(w + 33554432);       //  2,621,440
    ushort_t* Xp     = (ushort_t*)(w + 36175872);       //  1,310,720 (dead after xgemm)
    int*      flags  = (int*)(w + 36175872);            //  overlays Xp: 3*64*64B = 12,288
    ushort_t* h1hist = (ushort_t*)(w + 37486592);       // 33*131,072 = 4,325,376
    ushort_t* h2hist = (ushort_t*)(w + 41811968);       // 33*131,072 = 4,325,376
    float*    Qhist  = (float*)(w + 46137344);          // 32*1,048,576 = 33,554,432
    float*    h1f    = (float*)(w + 79691776);          //    262,144
    float*    c1f    = (float*)(w + 79953920);
    float*    h2f    = (float*)(w + 80216064);
    float*    c2f    = (float*)(w + 80478208);          // end 80,740,352

    // zero initial-state slots (h1(-1), h2(-1)) — layout-agnostic (all zeros)
    hipMemsetAsync(w + 37486592, 0, 131072, stream);
    hipMemsetAsync(w + 41811968, 0, 131072, stream);

    prep_inputs<<<3328, 256, 0, stream>>>(questions, embed, Xp, W_ih1, Wih1p);
    xgemm<<<dim3(32, 64), 256, 0, stream>>>(Xp, Wih1p, b_ih1, b_hh1, xg);

    // Xp is dead now; zero the flag region that overlays it (stream-ordered)
    hipMemsetAsync(w + 36175872, 0, 12288, stream);

    lstm_persist<<<NBLK, 256, 0, stream>>>(W_hh1, W_ih2, W_hh2, b_ih2, b_hh2,
                                           xg, qlen,
                                           h1hist, h2hist, Qhist,
                                           h1f, c1f, h2f, c2f, flags);

    write_out<<<4096, 256, 0, stream>>>(h1f, h2f, c1f, c2f, out);
}

// Round 9
// 529.267 us; speedup vs baseline: 1.2010x; 1.1700x over previous
//
#include <hip/hip_runtime.h>
#include <hip/hip_bf16.h>
#include <cstdint>

#define B_  64
#define T_  32
#define E_  300
#define EP  320      // padded K for the x-precompute GEMM
#define H_  1024
#define G4  4096     // 4*H
#define BH  65536    // B_*H_
#define NBLK 192     // persistent blocks: 64 L1 + 64 I2 + 64 H2

typedef __attribute__((ext_vector_type(8))) short bf16x8;
typedef __attribute__((ext_vector_type(4))) float f32x4;
typedef unsigned short ushort_t;

__device__ __forceinline__ bf16x8 load_b8(const ushort_t* p) {
    union { uint4 u; bf16x8 v; } c;
    c.u = *reinterpret_cast<const uint4*>(p);
    return c.v;
}

__device__ __forceinline__ ushort_t f2bf(float x) {
    union { float f; uint32_t u; } c; c.f = x;
    uint32_t r = c.u + 0x7fffu + ((c.u >> 16) & 1u);   // RNE
    return (ushort_t)(r >> 16);
}

__device__ __forceinline__ float sigm(float x) { return 1.0f / (1.0f + __expf(-x)); }

// agent-scope (cross-XCD write-through) stores for produced data; plain loads
// on the consumer side (unique buffer per timestep => no stale lines)
__device__ __forceinline__ void astore64(uint64_t* p, uint64_t v) {
    __hip_atomic_store(p, v, __ATOMIC_RELAXED, __HIP_MEMORY_SCOPE_AGENT);
}
__device__ __forceinline__ uint64_t packf2(float a, float b) {
    union { float f[2]; uint64_t u; } c; c.f[0] = a; c.f[1] = b; return c.u;
}

// ---- contention-free dataflow flags (proven ~neutral vs atomics; kept) ----
__device__ __forceinline__ void setflag(int* flags, int role, int js, int val) {
    __hip_atomic_store(&flags[(role * 64 + js) * 16], val,
                       __ATOMIC_RELAXED, __HIP_MEMORY_SCOPE_AGENT);
}
__device__ __forceinline__ void waitwave(const int* flags, int role, int target, int lane) {
    const int* p = &flags[(role * 64 + lane) * 16];
    int guard = 0;
    for (;;) {
        int v = __hip_atomic_load(p, __ATOMIC_RELAXED, __HIP_MEMORY_SCOPE_AGENT);
        if (__all(v >= target)) return;
        if (++guard > (1 << 22)) return;        // diagnostic bail-out (never hit when healthy)
        __builtin_amdgcn_s_sleep(1);
    }
}

// ---------------- fused prep kernel ----------------
// blocks [0,1280): embed gather+pad ; [1280,3328): W_ih1 pad+convert ;
// [3328,3392): zero h1hist/h2hist slot 0 (replaces 2 hipMemsetAsync dispatches)
__global__ void prep_inputs(const int* __restrict__ q, const float* __restrict__ table,
                            ushort_t* __restrict__ Xp,
                            const float* __restrict__ Wsrc, ushort_t* __restrict__ Wdst,
                            ushort_t* __restrict__ h1s0, ushort_t* __restrict__ h2s0) {
    int blk = blockIdx.x;
    if (blk < 1280) {
        int i = blk * 256 + threadIdx.x;
        const int n = B_ * T_ * EP;
        for (; i < n; i += 1280 * 256) {
            int r = i / EP, c = i - r * EP;
            Xp[i] = (c < E_) ? f2bf(table[q[r] * E_ + c]) : (ushort_t)0;
        }
    } else if (blk < 3328) {
        int i = (blk - 1280) * 256 + threadIdx.x;
        const int n = G4 * EP;
        for (; i < n; i += 2048 * 256) {
            int r = i / EP, c = i - r * EP;
            Wdst[i] = (c < E_) ? f2bf(Wsrc[r * E_ + c]) : (ushort_t)0;
        }
    } else {
        // 64 blocks x 256 threads x 1 uint4 = 16384 uint4 = 262,144 B
        int i = (blk - 3328) * 256 + threadIdx.x;       // 0..16383
        uint4 z = make_uint4(0, 0, 0, 0);
        if (i < 8192) reinterpret_cast<uint4*>(h1s0)[i] = z;
        else          reinterpret_cast<uint4*>(h2s0)[i - 8192] = z;
    }
}

// ---------------- x-part precompute GEMM ----------------
// xg[t][b][j][4gates] fp32 (gate-interleaved) -> role-0 reads ONE uint4/(b,j)
__launch_bounds__(256)
__global__ void xgemm(const ushort_t* __restrict__ Xp, const ushort_t* __restrict__ Wp,
                      const float* __restrict__ b_ih1, const float* __restrict__ b_hh1,
                      float* __restrict__ xg) {
    int mblk = blockIdx.x, nblk = blockIdx.y;
    int wave = threadIdx.x >> 6, lane = threadIdx.x & 63;
    int lm = lane & 15, lq = lane >> 4;
    int m0 = mblk * 64 + wave * 16;
    f32x4 acc[4];
    #pragma unroll
    for (int g = 0; g < 4; ++g) {
        int n = nblk * 64 + g * 16 + lm;
        float bv = b_ih1[n] + b_hh1[n];
        acc[g] = (f32x4){bv, bv, bv, bv};
    }
    for (int k0 = 0; k0 < EP; k0 += 32) {
        bf16x8 a = load_b8(Xp + (m0 + lm) * EP + k0 + lq * 8);
        #pragma unroll
        for (int g = 0; g < 4; ++g) {
            bf16x8 b = load_b8(Wp + (nblk * 64 + g * 16 + lm) * EP + k0 + lq * 8);
            acc[g] = __builtin_amdgcn_mfma_f32_16x16x32_bf16(a, b, acc[g], 0, 0, 0);
        }
    }
    #pragma unroll
    for (int g = 0; g < 4; ++g)
        #pragma unroll
        for (int r = 0; r < 4; ++r) {
            int m = m0 + lq * 4 + r;          // m = b*T + t
            int b = m >> 5, t = m & 31;
            int n = nblk * 64 + g * 16 + lm;  // raw 4H index
            int gate = n >> 10, j = n & 1023;
            xg[(((size_t)t * B_ + b) * H_ + j) * 4 + gate] = acc[g][r];
        }
}

// ---------------- persistent recurrence kernel ----------------
// 8 waves/block (512 thr) = 2 waves/SIMD for latency hiding.
// wave w: mi = w&3 (m-rows mi*16..+16), kh = w>>2 (K-half kh*512..+512).
// kh==0 <=> threadIdx.x<256. kh1 partials reduced via LDS into kh0.

__device__ __forceinline__ void gemm_half(const ushort_t* __restrict__ hslot,
                                          const ushort_t* __restrict__ wsf,
                                          int lm, int lq, int m0, int kh, f32x4 acc[4]) {
    const uint4* hr = reinterpret_cast<const uint4*>(hslot);
    const int rbase = (m0 + lm) * 2 + (lq & 1);
    const int cbo = lq >> 1;
    const int cb0 = kh * 32;                 // 16-col chunks per K-half
    uint4 buf[16];
    #pragma unroll
    for (int grp = 0; grp < 2; ++grp)
        #pragma unroll
        for (int i = 0; i < 8; ++i)
            buf[grp * 8 + i] = hr[(cb0 + grp * 16 + i * 2 + cbo) * 128 + rbase];
    #pragma unroll
    for (int grp = 0; grp < 2; ++grp)
        #pragma unroll
        for (int i = 0; i < 8; ++i) {
            int k0 = kh * 512 + grp * 256 + i * 32;
            union { uint4 u; bf16x8 v; } a; a.u = buf[grp * 8 + i];
            #pragma unroll
            for (int g = 0; g < 4; ++g) {
                int row = g * 16 + lm;
                bf16x8 bb = load_b8(wsf + row * 1024 + ((k0 + lq * 8) ^ ((lm & 7) << 3)));
                acc[g] = __builtin_amdgcn_mfma_f32_16x16x32_bf16(a.v, bb, acc[g], 0, 0, 0);
            }
        }
}

__device__ __forceinline__ void lstm_elem(const f32x4 acc[4], int r,
                                          float* c, float* h, ushort_t* hb) {
    float iv = sigm(acc[0][r]);
    float fv = sigm(acc[1][r]);
    float gv = tanhf(acc[2][r]);
    float ov = sigm(acc[3][r]);
    float cn = fv * c[r] + iv * gv;
    float hv = ov * tanhf(cn);
    c[r] = cn; h[r] = hv; hb[r] = f2bf(hv);
}

// col-major h-tile store: ONE contiguous 2KB burst per block (threads 0..255)
__device__ __forceinline__ void store_h_tile(ushort_t* slot, int js, const ushort_t* hst) {
    int tid = threadIdx.x;                     // caller guards tid < 256
    uint64_t v = reinterpret_cast<const uint64_t*>(hst)[tid];
    astore64(reinterpret_cast<uint64_t*>(slot) + js * 256 + tid, v);
}

__global__ __launch_bounds__(512) void lstm_persist(
    const float* __restrict__ Whh1, const float* __restrict__ Wih2,
    const float* __restrict__ Whh2,
    const float* __restrict__ b_ih2, const float* __restrict__ b_hh2,
    const float* __restrict__ xg, const int* __restrict__ qlen,
    ushort_t* __restrict__ h1hist,   // 33 slots of BH bf16, col-major; slot k = h1(k-1)
    ushort_t* __restrict__ h2hist,   // 33 slots of BH bf16, col-major; slot k = h2(k-1)
    float* __restrict__ Qhist,       // 32 slots of BH*4 fp32, gate-interleaved [b][j][4]
    float* __restrict__ h1f, float* __restrict__ c1f,
    float* __restrict__ h2f, float* __restrict__ c2f,
    int* __restrict__ flags)
{
    __shared__ ushort_t ws[64 * 1024];             // 131,072 B (swizzled)
    __shared__ __align__(16) ushort_t hstage[64][16];  // 2,048 B
    __shared__ f32x4 pacc[256][4];                 // 16,384 B -> total ~146 KB, 1 blk/CU

    const int blk  = blockIdx.x;
    const int role = blk >> 6;          // 0=L1, 1=I2, 2=H2
    const int js   = blk & 63;
    const int w    = threadIdx.x >> 6, lane = threadIdx.x & 63;
    const int mi   = w & 3, kh = w >> 2;
    const int lm = lane & 15, lq = lane >> 4;
    const int m0 = mi * 16;
    const int pidx = mi * 64 + lane;

    // ---- stage weight slice fp32 -> bf16 into LDS (once, swizzled) ----
    const float* Wsrc = (role == 0) ? Whh1 : (role == 1) ? Wih2 : Whh2;
    uint2* wsp = reinterpret_cast<uint2*>(ws);
    for (int idx = threadIdx.x; idx < 64 * 256; idx += 512) {
        int r = idx >> 8, c4 = idx & 255;
        int grow = (r >> 4) * H_ + js * 16 + (r & 15);
        float4 v = reinterpret_cast<const float4*>(Wsrc + (size_t)grow * H_)[c4];
        uint2 pk;
        pk.x = (uint32_t)f2bf(v.x) | ((uint32_t)f2bf(v.y) << 16);
        pk.y = (uint32_t)f2bf(v.z) | ((uint32_t)f2bf(v.w) << 16);
        wsp[r * 256 + (c4 ^ ((r & 7) << 1))] = pk;   // 8B-unit XOR == byte^((r&7)<<4)
    }
    __syncthreads();

    int q[4];
    #pragma unroll
    for (int r = 0; r < 4; ++r) q[r] = qlen[m0 + lq * 4 + r];

    float    c_reg[4]  = {0.f, 0.f, 0.f, 0.f};
    float    h_reg[4]  = {0.f, 0.f, 0.f, 0.f};
    ushort_t hb_reg[4] = {0, 0, 0, 0};

    if (role == 0) {
        for (int t = 0; t < T_; ++t) {
            f32x4 acc[4];
            #pragma unroll
            for (int g = 0; g < 4; ++g) acc[g] = (f32x4){0.f, 0.f, 0.f, 0.f};
            if (kh == 0) {                      // xg loads issue before the wait
                uint4 xq[4];
                #pragma unroll
                for (int r = 0; r < 4; ++r)
                    xq[r] = reinterpret_cast<const uint4*>(xg)
                            [((size_t)t * B_ + (m0 + lq * 4 + r)) * H_ + js * 16 + lm];
                #pragma unroll
                for (int r = 0; r < 4; ++r) {
                    union { uint32_t u; float f; } x0, x1, x2, x3;
                    x0.u = xq[r].x; x1.u = xq[r].y; x2.u = xq[r].z; x3.u = xq[r].w;
                    acc[0][r] = x0.f; acc[1][r] = x1.f;
                    acc[2][r] = x2.f; acc[3][r] = x3.f;
                }
            }
            if (t > 0) {
                if (w == 0) waitwave(flags, 0, t, lane);   // h1 slot t complete
                __syncthreads();
            }
            gemm_half(h1hist + (size_t)t * BH, ws, lm, lq, m0, kh, acc);
            if (kh == 1) {
                #pragma unroll
                for (int g = 0; g < 4; ++g) pacc[pidx][g] = acc[g];
            }
            __syncthreads();
            if (kh == 0) {
                #pragma unroll
                for (int g = 0; g < 4; ++g) acc[g] += pacc[pidx][g];
                #pragma unroll
                for (int r = 0; r < 4; ++r) {
                    if (t < q[r]) lstm_elem(acc, r, c_reg, h_reg, hb_reg);
                    hstage[m0 + lq * 4 + r][lm] = hb_reg[r];
                }
            }
            __syncthreads();
            if (threadIdx.x < 256)
                store_h_tile(h1hist + (size_t)(t + 1) * BH, js, &hstage[0][0]);
            __syncthreads();                    // drains vmcnt: stores visible
            if (threadIdx.x == 0) setflag(flags, 0, js, t + 1);
        }
        if (kh == 0) {
            #pragma unroll
            for (int r = 0; r < 4; ++r) {
                int b = m0 + lq * 4 + r, j = js * 16 + lm;
                h1f[b * H_ + j] = h_reg[r]; c1f[b * H_ + j] = c_reg[r];
            }
        }
    } else if (role == 1) {
        float bi[4];
        #pragma unroll
        for (int g = 0; g < 4; ++g) {
            int n = g * H_ + js * 16 + lm;
            bi[g] = b_ih2[n] + b_hh2[n];
        }
        for (int t = 0; t < T_; ++t) {
            if (w == 0) waitwave(flags, 0, t + 1, lane);   // h1 slot t+1 complete
            __syncthreads();
            f32x4 acc[4];
            #pragma unroll
            for (int g = 0; g < 4; ++g)
                acc[g] = (kh == 0) ? (f32x4){bi[g], bi[g], bi[g], bi[g]}
                                   : (f32x4){0.f, 0.f, 0.f, 0.f};
            gemm_half(h1hist + (size_t)(t + 1) * BH, ws, lm, lq, m0, kh, acc);
            if (kh == 1) {
                #pragma unroll
                for (int g = 0; g < 4; ++g) pacc[pidx][g] = acc[g];
            }
            __syncthreads();
            if (kh == 0) {
                #pragma unroll
                for (int g = 0; g < 4; ++g) acc[g] += pacc[pidx][g];
                uint64_t* Qw64 = (uint64_t*)(Qhist + (size_t)t * (4 * BH));
                #pragma unroll
                for (int r = 0; r < 4; ++r) {
                    int b = m0 + lq * 4 + r, j = js * 16 + lm;
                    size_t base = ((size_t)b * H_ + j) * 2;
                    astore64(Qw64 + base,     packf2(acc[0][r], acc[1][r]));
                    astore64(Qw64 + base + 1, packf2(acc[2][r], acc[3][r]));
                }
            }
            __syncthreads();                    // drain
            if (threadIdx.x == 0) setflag(flags, 1, js, t + 1);
        }
    } else {
        for (int t = 0; t < T_; ++t) {
            if (w == 0)               waitwave(flags, 1, t + 1, lane); // Q slot t done
            else if (w == 1 && t > 0) waitwave(flags, 2, t,     lane); // h2 slot t done
            __syncthreads();
            uint4 qp[4];
            if (kh == 0) {                      // Q loads complete under the GEMM
                const uint4* Qr = (const uint4*)(Qhist + (size_t)t * (4 * BH));
                #pragma unroll
                for (int r = 0; r < 4; ++r)
                    qp[r] = Qr[(size_t)(m0 + lq * 4 + r) * H_ + js * 16 + lm];
            }
            f32x4 acc[4];
            #pragma unroll
            for (int g = 0; g < 4; ++g) acc[g] = (f32x4){0.f, 0.f, 0.f, 0.f};
            gemm_half(h2hist + (size_t)t * BH, ws, lm, lq, m0, kh, acc);
            if (kh == 1) {
                #pragma unroll
                for (int g = 0; g < 4; ++g) pacc[pidx][g] = acc[g];
            }
            __syncthreads();
            if (kh == 0) {
                #pragma unroll
                for (int g = 0; g < 4; ++g) acc[g] += pacc[pidx][g];
                #pragma unroll
                for (int r = 0; r < 4; ++r) {
                    union { uint32_t u; float f; } x0, x1, x2, x3;
                    x0.u = qp[r].x; x1.u = qp[r].y; x2.u = qp[r].z; x3.u = qp[r].w;
                    acc[0][r] += x0.f; acc[1][r] += x1.f;
                    acc[2][r] += x2.f; acc[3][r] += x3.f;
                }
                #pragma unroll
                for (int r = 0; r < 4; ++r) {
                    if (t < q[r]) lstm_elem(acc, r, c_reg, h_reg, hb_reg);
                    hstage[m0 + lq * 4 + r][lm] = hb_reg[r];
                }
            }
            __syncthreads();
            if (threadIdx.x < 256)
                store_h_tile(h2hist + (size_t)(t + 1) * BH, js, &hstage[0][0]);
            __syncthreads();                    // drain
            if (t < T_ - 1 && threadIdx.x == 0) setflag(flags, 2, js, t + 1);
        }
        if (kh == 0) {
            #pragma unroll
            for (int r = 0; r < 4; ++r) {
                int b = m0 + lq * 4 + r, j = js * 16 + lm;
                h2f[b * H_ + j] = h_reg[r]; c2f[b * H_ + j] = c_reg[r];
            }
        }
    }
}

// ---------------- output fan-out ----------------
__global__ void write_out(const float* __restrict__ h1f, const float* __restrict__ h2f,
                          const float* __restrict__ c1f, const float* __restrict__ c2f,
                          float* __restrict__ out) {
    const long long EQ = (long long)B_ * H_ * 784;      // 51,380,224
    const long long n4 = (EQ + 4LL * B_ * H_) / 4;      // 12,910,592
    long long i4 = (long long)blockIdx.x * blockDim.x + threadIdx.x;
    long long stride = (long long)gridDim.x * blockDim.x;
    for (; i4 < n4; i4 += stride) {
        long long f = i4 * 4;
        float4 v;
        if (f < EQ) {
            long long bh = f / 784;
            float val = h2f[bh];
            v = make_float4(val, val, val, val);
        } else {
            long long r = f - EQ;
            int which = (int)(r >> 16);
            int j = (int)(r & 65535);
            const float* src = (which == 0) ? h1f : (which == 1) ? h2f : (which == 2) ? c1f : c2f;
            v = *reinterpret_cast<const float4*>(src + j);
        }
        reinterpret_cast<float4*>(out)[i4] = v;
    }
}

// ---------------- launch ----------------
extern "C" void kernel_launch(void* const* d_in, const int* in_sizes, int n_in,
                              void* d_out, int out_size, void* d_ws, size_t ws_size,
                              hipStream_t stream) {
    const int*   questions = (const int*)d_in[0];
    const int*   qlen      = (const int*)d_in[1];
    const float* embed     = (const float*)d_in[2];
    const float* W_ih1     = (const float*)d_in[3];
    const float* W_hh1     = (const float*)d_in[4];
    const float* b_ih1     = (const float*)d_in[5];
    const float* b_hh1     = (const float*)d_in[6];
    const float* W_ih2     = (const float*)d_in[7];
    const float* W_hh2     = (const float*)d_in[8];
    const float* b_ih2     = (const float*)d_in[9];
    const float* b_hh2     = (const float*)d_in[10];
    float* out = (float*)d_out;

    char* w = (char*)d_ws;
    float*    xg     = (float*)(w + 0);                 // 33,554,432
    ushort_t* Wih1p  = (ushort_t*)(w + 33554432);       //  2,621,440
    ushort_t* Xp     = (ushort_t*)(w + 36175872);       //  1,310,720 (dead after xgemm)
    int*      flags  = (int*)(w + 36175872);            //  overlays Xp: 3*64*64B = 12,288
    ushort_t* h1hist = (ushort_t*)(w + 37486592);       // 33*131,072 = 4,325,376
    ushort_t* h2hist = (ushort_t*)(w + 41811968);       // 33*131,072 = 4,325,376
    float*    Qhist  = (float*)(w + 46137344);          // 32*1,048,576 = 33,554,432
    float*    h1f    = (float*)(w + 79691776);          //    262,144
    float*    c1f    = (float*)(w + 79953920);
    float*    h2f    = (float*)(w + 80216064);
    float*    c2f    = (float*)(w + 80478208);          // end 80,740,352

    // h slot-0 zeroing now folded into prep_inputs (2 fewer dispatches)
    prep_inputs<<<3392, 256, 0, stream>>>(questions, embed, Xp, W_ih1, Wih1p,
                                          h1hist, h2hist);
    xgemm<<<dim3(32, 64), 256, 0, stream>>>(Xp, Wih1p, b_ih1, b_hh1, xg);

    // Xp is dead now; zero the flag region that overlays it (stream-ordered)
    hipMemsetAsync(w + 36175872, 0, 12288, stream);

    lstm_persist<<<NBLK, 512, 0, stream>>>(W_hh1, W_ih2, W_hh2, b_ih2, b_hh2,
                                           xg, qlen,
                                           h1hist, h2hist, Qhist,
                                           h1f, c1f, h2f, c2f, flags);

    write_out<<<4096, 256, 0, stream>>>(h1f, h2f, c1f, c2f, out);
}